// Round 1
// baseline (229.069 us; speedup 1.0000x reference)
//
#include <hip/hip_runtime.h>
#include <math.h>

#define BB 128   // batch
#define TT 8     // seq
#define DD 2048  // model dim
#define RR 4     // TT rank
#define VV 512   // vocab

// ws layout (floats):
//   fm    [BB][DD]            262144
//   alpha [BB][RR]            512
//   beta  [BB][RR]            512
//   marg  [BB][16]            2048
//   sel   [BB][TT][16]        16384
//   Cpart [4][64][BB][128]    4194304   (kh, vg, b, c)

// ---------------- phase A: T-mean + alpha/beta ----------------
__global__ __launch_bounds__(256) void phaseA(const float* __restrict__ inp,
                                              const float* __restrict__ w_alpha,
                                              const float* __restrict__ w_beta,
                                              float* __restrict__ fm,
                                              float* __restrict__ alpha,
                                              float* __restrict__ beta) {
    int b = blockIdx.x;
    int tid = threadIdx.x;
    float pa[4] = {0.f, 0.f, 0.f, 0.f};
    float pb[4] = {0.f, 0.f, 0.f, 0.f};
    const float* base = inp + (size_t)b * TT * DD;
    for (int d = tid; d < DD; d += 256) {
        float s = 0.f;
#pragma unroll
        for (int t = 0; t < TT; ++t) s += base[t * DD + d];
        float v = s * (1.0f / TT);
        fm[b * DD + d] = v;
        float4 wa = *(const float4*)(w_alpha + d * 4);
        float4 wb = *(const float4*)(w_beta + d * 4);
        pa[0] += v * wa.x; pa[1] += v * wa.y; pa[2] += v * wa.z; pa[3] += v * wa.w;
        pb[0] += v * wb.x; pb[1] += v * wb.y; pb[2] += v * wb.z; pb[3] += v * wb.w;
    }
    __shared__ float red[256][9];
#pragma unroll
    for (int r = 0; r < 4; ++r) { red[tid][r] = pa[r]; red[tid][4 + r] = pb[r]; }
    __syncthreads();
    for (int off = 128; off >= 1; off >>= 1) {
        if (tid < off) {
#pragma unroll
            for (int r = 0; r < 8; ++r) red[tid][r] += red[tid + off][r];
        }
        __syncthreads();
    }
    if (tid < 4) alpha[b * 4 + tid] = fabsf(red[0][tid]);
    else if (tid < 8) beta[b * 4 + (tid - 4)] = fabsf(red[0][tid]);
}

// ---------------- phase B: C = fm @ w_vocab, k-split, tiled ----------------
// grid 256 = 64 vg * 4 kh. Block tile: all 128 b x 128 cols (vg covers 8 vocab ids),
// K range [kh*512, kh*512+512). Thread tile 8x8.
__global__ __launch_bounds__(256) void phaseB(const float* __restrict__ fm,
                                              const float* __restrict__ wv,
                                              float* __restrict__ Cpart) {
    int bid = blockIdx.x;
    int vg = bid >> 2;   // [0,64)
    int kh = bid & 3;    // [0,4)
    int k0base = kh * 512;
    int tid = threadIdx.x;
    int ty = tid >> 4;   // [0,16) -> rows ty*8..
    int tx = tid & 15;   // [0,16) -> cols tx*8..

    __shared__ float As[32][132];  // [kk][b], +4 pad
    __shared__ float Ws[32][128];  // [kk][c]

    float acc[8][8];
#pragma unroll
    for (int i = 0; i < 8; ++i)
#pragma unroll
        for (int j = 0; j < 8; ++j) acc[i][j] = 0.f;

    for (int kc = 0; kc < 16; ++kc) {
        int k0 = k0base + kc * 32;
        // stage A: 128 rows x 32 k, transposed into LDS
#pragma unroll
        for (int n = 0; n < 4; ++n) {
            int u = n * 256 + tid;      // [0,1024)
            int bb = u >> 3;            // row
            int kq = u & 7;             // float4 within the 32-k window
            float4 a = *(const float4*)(fm + (size_t)bb * DD + k0 + kq * 4);
            As[kq * 4 + 0][bb] = a.x;
            As[kq * 4 + 1][bb] = a.y;
            As[kq * 4 + 2][bb] = a.z;
            As[kq * 4 + 3][bb] = a.w;
        }
        // stage W: 32 k x 128 cols. Local c = ii*32 + (vo*4+j); global col = ii*2048 + vg*32 + (c&31)
#pragma unroll
        for (int n = 0; n < 4; ++n) {
            int u = n * 256 + tid;      // [0,1024)
            int kk = u >> 5;            // [0,32)
            int cq = u & 31;            // float4 within 128 cols
            int ii = cq >> 3;
            int q = cq & 7;
            float4 w = *(const float4*)(wv + (size_t)(k0 + kk) * 8192 + ii * 2048 + vg * 32 + q * 4);
            *(float4*)&Ws[kk][cq * 4] = w;
        }
        __syncthreads();
#pragma unroll 8
        for (int kk = 0; kk < 32; ++kk) {
            float4 a0 = *(float4*)&As[kk][ty * 8];
            float4 a1 = *(float4*)&As[kk][ty * 8 + 4];
            float4 w0 = *(float4*)&Ws[kk][tx * 8];
            float4 w1 = *(float4*)&Ws[kk][tx * 8 + 4];
            float a[8] = {a0.x, a0.y, a0.z, a0.w, a1.x, a1.y, a1.z, a1.w};
            float w[8] = {w0.x, w0.y, w0.z, w0.w, w1.x, w1.y, w1.z, w1.w};
#pragma unroll
            for (int i = 0; i < 8; ++i)
#pragma unroll
                for (int j = 0; j < 8; ++j) acc[i][j] += a[i] * w[j];
        }
        __syncthreads();
    }
    // store partial tile: Cpart[kh][vg][b][c]
    size_t base = ((size_t)(kh * 64 + vg) * 128) * 128;
#pragma unroll
    for (int i = 0; i < 8; ++i) {
        int bb = ty * 8 + i;
        float4 s0 = make_float4(acc[i][0], acc[i][1], acc[i][2], acc[i][3]);
        float4 s1 = make_float4(acc[i][4], acc[i][5], acc[i][6], acc[i][7]);
        *(float4*)(Cpart + base + (size_t)bb * 128 + tx * 8) = s0;
        *(float4*)(Cpart + base + (size_t)bb * 128 + tx * 8 + 4) = s1;
    }
}

// ---------------- phase C: abs, marg-reduce over V, label select ----------------
__global__ __launch_bounds__(256) void phaseC(const float* __restrict__ Cpart,
                                              const int* __restrict__ labels,
                                              float* __restrict__ marg,
                                              float* __restrict__ sel) {
    int b = blockIdx.x;
    int tid = threadIdx.x;
    int lab[TT];
#pragma unroll
    for (int t = 0; t < TT; ++t) lab[t] = labels[b * TT + t];
    int c = tid & 127;           // constant per thread
    int i = c >> 5;
    int j = c & 3;
    int ij = i * 4 + j;
    int vo = (c & 31) >> 2;
    float msum = 0.f;
    __shared__ float smarg[16];
    if (tid < 16) smarg[tid] = 0.f;
    __syncthreads();
    const size_t slab = (size_t)64 * 128 * 128;
    for (int n = 0; n < 32; ++n) {
        int vg = n * 2 + (tid >> 7);
        size_t off = ((size_t)vg * 128 + b) * 128 + c;
        float s = Cpart[off] + Cpart[off + slab] + Cpart[off + 2 * slab] + Cpart[off + 3 * slab];
        float a = fabsf(s);
        msum += a;
        int v = vg * 8 + vo;
#pragma unroll
        for (int t = 0; t < TT; ++t)
            if (lab[t] == v) sel[((b * TT + t) << 4) + ij] = a;
    }
    atomicAdd(&smarg[ij], msum);
    __syncthreads();
    if (tid < 16) marg[(b << 4) + tid] = smarg[tid];
}

// ---------------- phase D: chain products, normalizer, loss ----------------
__global__ __launch_bounds__(128) void phaseD(const float* __restrict__ alpha,
                                              const float* __restrict__ beta,
                                              const float* __restrict__ marg,
                                              const float* __restrict__ sel,
                                              float* __restrict__ out) {
    int b = threadIdx.x;
    const float* sb = sel + b * TT * 16;
    float res[16], tmp[16], mm[16], zm[16];
#pragma unroll
    for (int e = 0; e < 16; ++e) res[e] = sb[e];
    for (int t = 1; t < TT; ++t) {
        const float* m = sb + t * 16;
#pragma unroll
        for (int i = 0; i < 4; ++i)
#pragma unroll
            for (int j = 0; j < 4; ++j) {
                float s = 0.f;
#pragma unroll
                for (int k = 0; k < 4; ++k) s += res[i * 4 + k] * m[k * 4 + j];
                tmp[i * 4 + j] = s;
            }
#pragma unroll
        for (int e = 0; e < 16; ++e) res[e] = tmp[e];
    }
#pragma unroll
    for (int e = 0; e < 16; ++e) { mm[e] = marg[b * 16 + e]; zm[e] = mm[e]; }
    for (int st = 0; st < TT; ++st) {  // zm = marg^(T+1)
#pragma unroll
        for (int i = 0; i < 4; ++i)
#pragma unroll
            for (int j = 0; j < 4; ++j) {
                float s = 0.f;
#pragma unroll
                for (int k = 0; k < 4; ++k) s += zm[i * 4 + k] * mm[k * 4 + j];
                tmp[i * 4 + j] = s;
            }
#pragma unroll
        for (int e = 0; e < 16; ++e) zm[e] = tmp[e];
    }
    float u = 0.f, z = 0.f;
#pragma unroll
    for (int i = 0; i < 4; ++i) {
        float ai = alpha[b * 4 + i];
#pragma unroll
        for (int j = 0; j < 4; ++j) {
            float bj = beta[b * 4 + j];
            u += ai * res[i * 4 + j] * bj;
            z += ai * zm[i * 4 + j] * bj;
        }
    }
    float loss = logf(z) - logf(u);
    __shared__ float red[128];
    red[b] = loss;
    __syncthreads();
    for (int off = 64; off >= 1; off >>= 1) {
        if (b < off) red[b] += red[b + off];
        __syncthreads();
    }
    if (b == 0) out[0] = red[0] * (1.0f / BB);
}

extern "C" void kernel_launch(void* const* d_in, const int* in_sizes, int n_in,
                              void* d_out, int out_size, void* d_ws, size_t ws_size,
                              hipStream_t stream) {
    const float* inp     = (const float*)d_in[0];  // [128,8,2048]
    const int*   labels  = (const int*)d_in[1];    // [128,8]
    const float* w_alpha = (const float*)d_in[2];  // [2048,4]
    const float* w_beta  = (const float*)d_in[3];  // [2048,4]
    const float* wv      = (const float*)d_in[4];  // [2048,8192]
    float* out = (float*)d_out;

    float* ws    = (float*)d_ws;
    float* fm    = ws;                       // 262144
    float* alpha = fm + BB * DD;             // 512
    float* beta  = alpha + BB * RR;          // 512
    float* marg  = beta + BB * RR;           // 2048
    float* sel   = marg + BB * 16;           // 16384
    float* Cpart = sel + BB * TT * 16;       // 4*64*128*128

    phaseA<<<BB, 256, 0, stream>>>(inp, w_alpha, w_beta, fm, alpha, beta);
    phaseB<<<256, 256, 0, stream>>>(fm, wv, Cpart);
    phaseC<<<BB, 256, 0, stream>>>(Cpart, labels, marg, sel);
    phaseD<<<1, 128, 0, stream>>>(alpha, beta, marg, sel, out);
}

// Round 2
// 128.344 us; speedup vs baseline: 1.7848x; 1.7848x over previous
//
#include <hip/hip_runtime.h>
#include <math.h>

#define BB 128   // batch
#define TT 8     // seq
#define DD 2048  // model dim
#define RR 4     // TT rank
#define VV 512   // vocab

typedef __attribute__((ext_vector_type(8))) short short8;
typedef __attribute__((ext_vector_type(4))) float v4f;

__device__ __forceinline__ unsigned pack_bf16(float x, float y) {
    union { float f; unsigned u; } a, b;
    a.f = x; b.f = y;
    unsigned ua = a.u + 0x7fffu + ((a.u >> 16) & 1u);
    unsigned ub = b.u + 0x7fffu + ((b.u >> 16) & 1u);
    return (ua >> 16) | (ub & 0xffff0000u);
}

// ---------------- phase A: T-mean -> fmb(bf16), alpha/beta partial dots ----------------
// grid 256 = (b, half-of-D). alpha/beta accumulated via global atomics (abs applied in phaseD).
__global__ __launch_bounds__(256) void phaseA(const float* __restrict__ inp,
                                              const float* __restrict__ w_alpha,
                                              const float* __restrict__ w_beta,
                                              unsigned short* __restrict__ fmb,
                                              float* __restrict__ alphaA,
                                              float* __restrict__ betaA) {
    int bid = blockIdx.x;
    int b = bid >> 1, half = bid & 1;
    int tid = threadIdx.x;
    const float* base = inp + (size_t)b * TT * DD;
    float pa[4] = {0.f, 0.f, 0.f, 0.f};
    float pb[4] = {0.f, 0.f, 0.f, 0.f};
#pragma unroll
    for (int i = 0; i < 4; ++i) {
        int d = half * 1024 + i * 256 + tid;
        float s = 0.f;
#pragma unroll
        for (int t = 0; t < TT; ++t) s += base[t * DD + d];
        float v = s * (1.0f / TT);
        union { float f; unsigned u; } cv; cv.f = v;
        unsigned r = cv.u + 0x7fffu + ((cv.u >> 16) & 1u);
        fmb[b * DD + d] = (unsigned short)(r >> 16);
        float4 wa = *(const float4*)(w_alpha + d * 4);
        float4 wb = *(const float4*)(w_beta + d * 4);
        pa[0] += v * wa.x; pa[1] += v * wa.y; pa[2] += v * wa.z; pa[3] += v * wa.w;
        pb[0] += v * wb.x; pb[1] += v * wb.y; pb[2] += v * wb.z; pb[3] += v * wb.w;
    }
#pragma unroll
    for (int r = 0; r < 4; ++r) {
        for (int m = 1; m < 64; m <<= 1) {
            pa[r] += __shfl_xor(pa[r], m);
            pb[r] += __shfl_xor(pb[r], m);
        }
    }
    if ((tid & 63) == 0) {
#pragma unroll
        for (int r = 0; r < 4; ++r) {
            atomicAdd(&alphaA[b * 4 + r], pa[r]);
            atomicAdd(&betaA[b * 4 + r], pb[r]);
        }
    }
}

// ---------------- phase B: bf16 MFMA GEMM + fused abs/marg/select epilogue ----------------
// grid 256 blocks: block nb covers cols [nb*32, nb*32+32); 512 thr = 8 waves, wave w rows [w*16,+16).
// K = 2048 in 16 chunks of 128; Ws double-buffered; A-frags direct from L2-resident fmb.
__global__ __launch_bounds__(512, 2) void phaseB(const unsigned short* __restrict__ fmb,
                                                 const float* __restrict__ wv,
                                                 const int* __restrict__ labels,
                                                 float* __restrict__ margA,
                                                 float* __restrict__ sel) {
    __shared__ unsigned short Ws[2][32][136];  // [buf][n][k+pad], bf16
    __shared__ int slab[BB * TT];

    const int tid = threadIdx.x;
    const int nb = blockIdx.x;
    const int col0 = nb * 32;

    slab[tid] = labels[tid];
    slab[tid + 512] = labels[tid + 512];

    const int nq = tid & 7;        // float4 group within 32 cols
    const int kp = tid >> 3;       // 0..63 -> k pair 2kp, 2kp+1
    const int w = tid >> 6;        // wave
    const int lane = tid & 63;
    const int m15 = lane & 15;
    const int q = lane >> 4;

    const float* wbase = wv + (size_t)(2 * kp) * 8192 + col0 + nq * 4;
    const unsigned short* abase = fmb + (w * 16 + m15) * DD + q * 8;

    v4f acc0 = {0.f, 0.f, 0.f, 0.f};
    v4f acc1 = {0.f, 0.f, 0.f, 0.f};
    short8 afr[2][4];
    float4 sw0, sw1;

    // prologue: chunk 0
    sw0 = *(const float4*)(wbase);
    sw1 = *(const float4*)(wbase + 8192);
#pragma unroll
    for (int ks = 0; ks < 4; ++ks) afr[0][ks] = *(const short8*)(abase + ks * 32);
    {
        const float* f0 = (const float*)&sw0;
        const float* f1 = (const float*)&sw1;
#pragma unroll
        for (int j = 0; j < 4; ++j)
            *(unsigned*)&Ws[0][nq * 4 + j][2 * kp] = pack_bf16(f0[j], f1[j]);
    }
    __syncthreads();

    for (int c = 0; c < 16; ++c) {
        const int cur = c & 1;
        if (c < 15) {
            const float* wp = wbase + (size_t)(c + 1) * 128 * 8192;
            sw0 = *(const float4*)(wp);
            sw1 = *(const float4*)(wp + 8192);
            const unsigned short* ap = abase + (c + 1) * 128;
#pragma unroll
            for (int ks = 0; ks < 4; ++ks) afr[1 - cur][ks] = *(const short8*)(ap + ks * 32);
        }
#pragma unroll
        for (int ks = 0; ks < 4; ++ks) {
            short8 b0 = *(const short8*)&Ws[cur][m15][ks * 32 + q * 8];
            short8 b1 = *(const short8*)&Ws[cur][16 + m15][ks * 32 + q * 8];
            acc0 = __builtin_amdgcn_mfma_f32_16x16x32_bf16(afr[cur][ks], b0, acc0, 0, 0, 0);
            acc1 = __builtin_amdgcn_mfma_f32_16x16x32_bf16(afr[cur][ks], b1, acc1, 0, 0, 0);
        }
        if (c < 15) {
            const float* f0 = (const float*)&sw0;
            const float* f1 = (const float*)&sw1;
#pragma unroll
            for (int j = 0; j < 4; ++j)
                *(unsigned*)&Ws[1 - cur][nq * 4 + j][2 * kp] = pack_bf16(f0[j], f1[j]);
        }
        __syncthreads();
    }

    // epilogue: |acc| -> marg atomics + label-select scatter. D layout: row=q*4+r, col=m15.
    const int vbase = (nb & 63) * 8;
    const int iblk = nb >> 6;
    const int j = m15 & 3;
    const int v0 = vbase + (m15 >> 2);   // col = m15
    const float* a0p = (const float*)&acc0;
    const float* a1p = (const float*)&acc1;
#pragma unroll
    for (int r = 0; r < 4; ++r) {
        int m = w * 16 + q * 4 + r;
        float a0 = fabsf(a0p[r]);        // col = m15       -> v0
        float a1 = fabsf(a1p[r]);        // col = 16 + m15  -> v0 + 4
        float s = a0 + a1;
        s += __shfl_xor(s, 4);
        s += __shfl_xor(s, 8);
        if ((lane & 12) == 0) atomicAdd(&margA[m * 16 + iblk * 4 + j], s);
#pragma unroll
        for (int t = 0; t < TT; ++t) {
            int lv = slab[m * 8 + t];
            if (lv == v0)     sel[(m * 8 + t) * 16 + iblk * 4 + j] = a0;
            if (lv == v0 + 4) sel[(m * 8 + t) * 16 + iblk * 4 + j] = a1;
        }
    }
}

// ---------------- phase D: chain products, normalizer, loss ----------------
__global__ __launch_bounds__(128) void phaseD(const float* __restrict__ alpha,
                                              const float* __restrict__ beta,
                                              const float* __restrict__ marg,
                                              const float* __restrict__ sel,
                                              float* __restrict__ out) {
    int b = threadIdx.x;
    const float* sb = sel + b * TT * 16;
    float res[16], tmp[16], mm[16], zm[16];
#pragma unroll
    for (int e = 0; e < 16; ++e) res[e] = sb[e];
    for (int t = 1; t < TT; ++t) {
        const float* m = sb + t * 16;
#pragma unroll
        for (int i = 0; i < 4; ++i)
#pragma unroll
            for (int jj = 0; jj < 4; ++jj) {
                float s = 0.f;
#pragma unroll
                for (int k = 0; k < 4; ++k) s += res[i * 4 + k] * m[k * 4 + jj];
                tmp[i * 4 + jj] = s;
            }
#pragma unroll
        for (int e = 0; e < 16; ++e) res[e] = tmp[e];
    }
#pragma unroll
    for (int e = 0; e < 16; ++e) { mm[e] = marg[b * 16 + e]; zm[e] = mm[e]; }
    for (int st = 0; st < TT; ++st) {
#pragma unroll
        for (int i = 0; i < 4; ++i)
#pragma unroll
            for (int jj = 0; jj < 4; ++jj) {
                float s = 0.f;
#pragma unroll
                for (int k = 0; k < 4; ++k) s += zm[i * 4 + k] * mm[k * 4 + jj];
                tmp[i * 4 + jj] = s;
            }
#pragma unroll
        for (int e = 0; e < 16; ++e) zm[e] = tmp[e];
    }
    float u = 0.f, z = 0.f;
#pragma unroll
    for (int i = 0; i < 4; ++i) {
        float ai = fabsf(alpha[b * 4 + i]);
#pragma unroll
        for (int jj = 0; jj < 4; ++jj) {
            float bj = fabsf(beta[b * 4 + jj]);
            u += ai * res[i * 4 + jj] * bj;
            z += ai * zm[i * 4 + jj] * bj;
        }
    }
    float loss = logf(z) - logf(u);
    __shared__ float red[128];
    red[b] = loss;
    __syncthreads();
    for (int off = 64; off >= 1; off >>= 1) {
        if (b < off) red[b] += red[b + off];
        __syncthreads();
    }
    if (b == 0) out[0] = red[0] * (1.0f / BB);
}

extern "C" void kernel_launch(void* const* d_in, const int* in_sizes, int n_in,
                              void* d_out, int out_size, void* d_ws, size_t ws_size,
                              hipStream_t stream) {
    const float* inp     = (const float*)d_in[0];  // [128,8,2048]
    const int*   labels  = (const int*)d_in[1];    // [128,8]
    const float* w_alpha = (const float*)d_in[2];  // [2048,4]
    const float* w_beta  = (const float*)d_in[3];  // [2048,4]
    const float* wv      = (const float*)d_in[4];  // [2048,8192]
    float* out = (float*)d_out;

    float* ws    = (float*)d_ws;
    float* alpha = ws;                         // 512
    float* beta  = ws + 512;                   // 512
    float* marg  = ws + 1024;                  // 2048
    float* sel   = ws + 3072;                  // 16384
    unsigned short* fmb = (unsigned short*)(ws + 3072 + 16384);  // 128*2048 bf16

    // zero alpha/beta/marg (atomically accumulated)
    hipMemsetAsync(ws, 0, 3072 * sizeof(float), stream);

    phaseA<<<256, 256, 0, stream>>>(inp, w_alpha, w_beta, fmb, alpha, beta);
    phaseB<<<256, 512, 0, stream>>>(fmb, wv, labels, marg, sel);
    phaseD<<<1, 128, 0, stream>>>(alpha, beta, marg, sel, out);
}